// Round 11
// baseline (179.026 us; speedup 1.0000x reference)
//
#include <hip/hip_runtime.h>

// B=4, S=2048, D=768, H=12, E=64, M=B*S=8192, N_qkv=2304
// scale = log2(e)/sqrt(S) folded into Q at QKV-GEMM epilogue (softmax via exp2).

typedef __bf16 bf16x8 __attribute__((ext_vector_type(8)));
typedef __bf16 bf16x4 __attribute__((ext_vector_type(4)));
typedef float  f32x4  __attribute__((ext_vector_type(4)));
typedef float  f32x16 __attribute__((ext_vector_type(16)));
typedef unsigned u32x4 __attribute__((ext_vector_type(4)));

#define MFMA16(a,b,c) __builtin_amdgcn_mfma_f32_16x16x32_bf16((a),(b),(c),0,0,0)
#define MFMA32(a,b,c) __builtin_amdgcn_mfma_f32_32x32x16_bf16((a),(b),(c),0,0,0)
// 1/sqrt(2048) * log2(e): scores land in log2 domain -> exp2 only, no mul.
#define QSCALE2 (0.022097086912079612f * 1.4426950408889634f)

__device__ __forceinline__ void gload16(const void* g, void* l) {
  __builtin_amdgcn_global_load_lds((const __attribute__((address_space(1))) void*)g,
                                   (__attribute__((address_space(3))) void*)l, 16, 0, 0);
}

// ---------------- pack: fp32 -> bf16 (+ weight transposes) ----------------
__global__ __launch_bounds__(256) void pack_kernel(
    const float* __restrict__ x, const float* __restrict__ Wq,
    const float* __restrict__ Wk, const float* __restrict__ Wv,
    const float* __restrict__ Wo,
    __bf16* __restrict__ xb, __bf16* __restrict__ wqkv, __bf16* __restrict__ wot) {
  int tid = blockIdx.x * 256 + threadIdx.x;
  int nth = gridDim.x * 256;
  for (int i = tid; i < 8192 * 768 / 4; i += nth) {
    float4 v = ((const float4*)x)[i];
    bf16x4 o; o[0] = (__bf16)v.x; o[1] = (__bf16)v.y; o[2] = (__bf16)v.z; o[3] = (__bf16)v.w;
    ((bf16x4*)xb)[i] = o;
  }
  for (int i = tid; i < 3 * 768 * 768; i += nth) {
    int n = i / 768, d = i - n * 768;
    int p = n / 768;
    int wn = n - p * 768;
    int h = wn >> 6, e = wn & 63;
    const float* W = (p == 0) ? Wq : (p == 1) ? Wk : Wv;
    wqkv[i] = (__bf16)W[(h * 768 + d) * 64 + e];
  }
  for (int i = tid; i < 768 * 768; i += nth) {
    int n = i / 768, k = i - n * 768;
    wot[i] = (__bf16)Wo[k * 768 + n];
  }
}

// -- GEMM core v11: 128x128 tile, BK=32, 3-buffer COUNTED-vmcnt pipeline (T4) --
// r8/r9/r10 showed gemm_qkv invariant at ~69.5us across single-buf/dbuf/small-
// tile: the shared constraint was __syncthreads' implicit vmcnt(0) draining the
// prefetch every K-step. v11: rotating 3-buffer schedule, per step:
//   s_waitcnt vmcnt(4)   <- own 4 loads for THIS step landed; next step's 4
//                           loads stay in flight ACROSS the barrier (T4, m218)
//   s_barrier (raw)      <- all waves' loads for this buf landed
//   issue 4 loads for step t+2 into buf (t+2)%3
//   ds_read buf t%3 + 16 MFMA
// Hazard proof: buf t%3 is overwritten by the stage issued after barrier t+1;
// all waves' reads of buf t%3 are consumed (compiler lgkmcnt) before their
// MFMAs, which precede barrier t+1 in program order. Tail: vmcnt(0) at t=23.
// LDS 48KB (3 blocks/CU); bank-deswizzle kept (read col co, global src col cc).
#define GEMM_STEP(B_, T_)                                                         \
  {                                                                               \
    if ((T_) < 23) asm volatile("s_waitcnt vmcnt(4)" ::: "memory");               \
    else           asm volatile("s_waitcnt vmcnt(0)" ::: "memory");               \
    __builtin_amdgcn_s_barrier();                                                 \
    if ((T_) < 22) {                                                              \
      const int kk_ = ((T_) + 2) * 32;                                            \
      const int sb_ = ((B_) + 2) % 3;                                             \
      gload16(ga0 + kk_, lA + sb_ * 8192);                                        \
      gload16(ga1 + kk_, lA + sb_ * 8192 + 4096);                                 \
      gload16(gb0 + kk_, lB + sb_ * 8192);                                        \
      gload16(gb1 + kk_, lB + sb_ * 8192 + 4096);                                 \
    }                                                                             \
    bf16x8 af[4], bfv[4];                                                         \
    _Pragma("unroll") for (int mt = 0; mt < 4; ++mt)                              \
      af[mt] = *(const bf16x8*)((char*)As + (B_) * 8192 +                         \
                                (wr * 64 + mt * 16 + ln) * 64 + co * 2);          \
    _Pragma("unroll") for (int nt = 0; nt < 4; ++nt)                              \
      bfv[nt] = *(const bf16x8*)((char*)Bs + (B_) * 8192 +                        \
                                 (wc * 64 + nt * 16 + ln) * 64 + co * 2);         \
    _Pragma("unroll") for (int mt = 0; mt < 4; ++mt)                              \
      _Pragma("unroll") for (int nt = 0; nt < 4; ++nt)                            \
        acc[mt][nt] = MFMA16(af[mt], bfv[nt], acc[mt][nt]);                       \
  }

#define GEMM_CORE(A_, Bt_, m0_, n0_)                                              \
  __shared__ __align__(16) __bf16 As[3][128 * 32];                                \
  __shared__ __align__(16) __bf16 Bs[3][128 * 32];                                \
  const int tid = threadIdx.x;                                                    \
  const int w = tid >> 6, lane = tid & 63, ln = lane & 15, hi = lane >> 4;        \
  const int wr = w >> 1, wc = w & 1;                                              \
  f32x4 acc[4][4];                                                                \
  {                                                                               \
    f32x4 z = {0.f, 0.f, 0.f, 0.f};                                               \
    _Pragma("unroll") for (int i = 0; i < 4; ++i)                                 \
      _Pragma("unroll") for (int j = 0; j < 4; ++j) acc[i][j] = z;                \
  }                                                                               \
  const int co = 8 * (hi ^ ((ln >> 1) & 3));   /* swizzled read col (elements) */ \
  {                                                                               \
    const int r0 = tid >> 2;                                                      \
    const int cc = ((tid & 3) * 8) ^ (((r0 >> 1) & 3) << 3); /* swizzled src */   \
    const __bf16* ga0 = A_ + (size_t)(m0_ + r0) * 768 + cc;                       \
    const __bf16* ga1 = A_ + (size_t)(m0_ + 64 + r0) * 768 + cc;                  \
    const __bf16* gb0 = Bt_ + (size_t)(n0_ + r0) * 768 + cc;                      \
    const __bf16* gb1 = Bt_ + (size_t)(n0_ + 64 + r0) * 768 + cc;                 \
    char* lA = (char*)As + w * 1024;   /* wave-uniform dest (lane*16 implicit) */ \
    char* lB = (char*)Bs + w * 1024;                                              \
    /* prologue: L0 -> buf0, L1 -> buf1 */                                        \
    gload16(ga0, lA);       gload16(ga1, lA + 4096);                              \
    gload16(gb0, lB);       gload16(gb1, lB + 4096);                              \
    gload16(ga0 + 32, lA + 8192);  gload16(ga1 + 32, lA + 8192 + 4096);           \
    gload16(gb0 + 32, lB + 8192);  gload16(gb1 + 32, lB + 8192 + 4096);           \
    for (int t = 0; t < 24; t += 3) {                                             \
      GEMM_STEP(0, t)                                                             \
      GEMM_STEP(1, t + 1)                                                         \
      GEMM_STEP(2, t + 2)                                                         \
    }                                                                             \
  }

__global__ __launch_bounds__(256) void gemm_qkv(
    const __bf16* __restrict__ A, const __bf16* __restrict__ Bt,
    const float* __restrict__ bq, const float* __restrict__ bk,
    const float* __restrict__ bv,
    __bf16* __restrict__ qb, __bf16* __restrict__ kb, __bf16* __restrict__ vt) {
  // T1: XCD-aware bijective swizzle (nwg=1152, 144/XCD; consecutive swz share A-panels)
  const int lin = blockIdx.y * 18 + blockIdx.x;
  const int swzb = (lin & 7) * 144 + (lin >> 3);
  const int m0 = (swzb / 18) * 128, n0 = (swzb % 18) * 128;
  GEMM_CORE(A, Bt, m0, n0)
  const int p = n0 / 768;
  const float* bias = (p == 0) ? bq : (p == 1) ? bk : bv;
  const float sc = (p == 0) ? QSCALE2 : 1.0f;
#pragma unroll
  for (int nt = 0; nt < 4; ++nt) {
    int n = n0 + wc * 64 + nt * 16 + ln;
    int wn = n - p * 768;
    int h = wn >> 6, e = wn & 63;
    float bb = bias[wn];
#pragma unroll
    for (int mt = 0; mt < 4; ++mt) {
      int mrow = m0 + wr * 64 + mt * 16 + hi * 4;
      int b = mrow >> 11, s0 = mrow & 2047;
      if (p == 2) {
        bf16x4 pk;
#pragma unroll
        for (int r = 0; r < 4; ++r) pk[r] = (__bf16)(acc[mt][nt][r] + bb);
        *(bf16x4*)&vt[(((size_t)b * 12 + h) * 64 + e) * 2048 + s0] = pk;
      } else {
        __bf16* dst = (p == 0) ? qb : kb;
#pragma unroll
        for (int r = 0; r < 4; ++r)
          dst[(((size_t)b * 12 + h) * 2048 + s0 + r) * 64 + e] =
              (__bf16)((acc[mt][nt][r] + bb) * sc);
      }
    }
  }
}

__global__ __launch_bounds__(256) void gemm_proj(
    const __bf16* __restrict__ A, const __bf16* __restrict__ Bt,
    const float* __restrict__ bo, const float* __restrict__ xres,
    float* __restrict__ hout) {
  // T1 swizzle (nwg=384, 48/XCD)
  const int lin = blockIdx.y * 6 + blockIdx.x;
  const int swzb = (lin & 7) * 48 + (lin >> 3);
  const int m0 = (swzb / 6) * 128, n0 = (swzb % 6) * 128;
  GEMM_CORE(A, Bt, m0, n0)
#pragma unroll
  for (int nt = 0; nt < 4; ++nt) {
    int n = n0 + wc * 64 + nt * 16 + ln;
    float bb = bo[n];
#pragma unroll
    for (int mt = 0; mt < 4; ++mt) {
      int mrow = m0 + wr * 64 + mt * 16 + hi * 4;
#pragma unroll
      for (int r = 0; r < 4; ++r) {
        size_t idx = (size_t)(mrow + r) * 768 + n;
        hout[idx] = acc[mt][nt][r] + bb + xres[idx];
      }
    }
  }
}

// ---------------- flash attention: 32x32 MFMA, in-register P, swizzled LDS ----
// ROUND-4 VERSION (best measured: 69us). grid (48,16): block = (b*12+h, 128 q).
// 4 waves x 32 q-rows. KVBLK=64. Swapped mfma(K,Q): lane (q=lane&31, h=lane>>5)
// holds P[q][kv=(r&3)+8*(r>>2)+4h]. cvt_pk + permlane32_swap builds PV A-frags
// in-register. K/V tiles [64][64] bf16, XOR-swizzle byte^=((row&7)<<4), staged
// via global_load_lds with pre-swizzled global SOURCE; ^32s col steps (XOR dom).
// lsum via MFMA(P, ones): lacc[r] = denom for the SAME q-row as cacc[*][r].
// Structure is at its floor at 3 waves/SIMD (reg-capped: 84 arch + ~48 acc);
// v5 no-LDS (186us, scatter-bound), v6 T15 (spilled), v7 kv-split (no occ gain,
// +11us overhead) all refuted alternatives. blockIdx identity: XCD = bh%8.
__global__ __launch_bounds__(256, 3) void attn_kernel(
    const __bf16* __restrict__ qb, const __bf16* __restrict__ kb,
    const __bf16* __restrict__ vt, __bf16* __restrict__ ctx) {
  // LDS: K dbuf [2][8KB] at 0, V^T dbuf [2][8KB] at 16384. 32 KiB total.
  __shared__ __align__(16) char lds[32768];
  const int tid = threadIdx.x;
  const int w = tid >> 6, lane = tid & 63;
  const int l31 = lane & 31, h = lane >> 5;
  const int bh = blockIdx.x;
  const int q0 = blockIdx.y * 128 + w * 32;

  // ---- staging: thread covers linear LDS bytes o=tid*16 (round0) and +4096 (round1)
  const int o0 = tid * 16, o1 = o0 + 4096;
  const int r0s = o0 >> 7, cb0 = o0 & 127;
  const int r1s = o1 >> 7, cb1 = o1 & 127;
  const char* kgb = (const char*)(kb + (size_t)bh * 2048 * 64);
  const char* vgb = (const char*)(vt + (size_t)bh * 64 * 2048);
  const char* ksrc0 = kgb + r0s * 128 + (cb0 ^ ((r0s & 7) << 4));
  const char* ksrc1 = kgb + r1s * 128 + (cb1 ^ ((r1s & 7) << 4));
  const char* vsrc0 = vgb + r0s * 4096 + (cb0 ^ ((r0s & 7) << 4));
  const char* vsrc1 = vgb + r1s * 4096 + (cb1 ^ ((r1s & 7) << 4));
  char* kl0 = lds + w * 1024;            // wave-uniform LDS base (lane*16 implicit)
  char* vl0 = lds + 16384 + w * 1024;

#define STAGE(t_, b_) do {                                   \
    gload16(ksrc0 + (size_t)(t_) * 8192, kl0 + (b_) * 8192); \
    gload16(ksrc1 + (size_t)(t_) * 8192, kl0 + (b_) * 8192 + 4096); \
    gload16(vsrc0 + (size_t)(t_) * 128,  vl0 + (b_) * 8192); \
    gload16(vsrc1 + (size_t)(t_) * 128,  vl0 + (b_) * 8192 + 4096); \
  } while (0)

  // ---- Q fragments (B-operand of mfma(K,Q)): col=q=l31, k(e)=16s+8h+j
  const __bf16* qp = qb + ((size_t)bh * 2048 + q0 + l31) * 64 + h * 8;
  bf16x8 qf[4];
#pragma unroll
  for (int s = 0; s < 4; ++s) qf[s] = *(const bf16x8*)(qp + 16 * s);

  // ---- per-lane swizzled LDS read addresses, precomputed (loop-invariant)
  const int swz = (l31 & 7) << 4;
  const int krd = l31 * 128 + ((h * 16) ^ swz);
  const int vrd = 16384 + l31 * 128 + ((h * 16) ^ swz);
  int ka_[8], va_[8];
#pragma unroll
  for (int kvt = 0; kvt < 2; ++kvt)
#pragma unroll
    for (int s = 0; s < 4; ++s) ka_[kvt * 4 + s] = (krd + kvt * 4096) ^ (s * 32);
#pragma unroll
  for (int ks = 0; ks < 4; ++ks)
#pragma unroll
    for (int et = 0; et < 2; ++et) va_[ks * 2 + et] = (vrd + et * 4096) ^ (ks * 32);

  // ---- loop-invariant constants: zero C-init, ones B-frag for lsum-MFMA
  f32x16 FZ;
#pragma unroll
  for (int r = 0; r < 16; ++r) FZ[r] = 0.f;
  bf16x8 onesf;
#pragma unroll
  for (int j = 0; j < 8; ++j) onesf[j] = (__bf16)1.0f;

  f32x16 lacc = FZ;
  f32x16 cacc[2];
  cacc[0] = FZ; cacc[1] = FZ;

  STAGE(0, 0);
  __syncthreads();

#define PKPAIR(dst_, i_)                                                       \
  {                                                                            \
    float pa_ = __builtin_amdgcn_exp2f(sa[2 * (i_)]);                          \
    float pb_ = __builtin_amdgcn_exp2f(sa[2 * (i_) + 1]);                      \
    asm("v_cvt_pk_bf16_f32 %0, %1, %2" : "=v"(dst_) : "v"(pa_), "v"(pb_));     \
  }

#define TILEBODY(B_, T_)                                                       \
  {                                                                            \
    if ((T_) < 31) STAGE((T_) + 1, (B_) ^ 1);                                  \
    bf16x8 kf[2][4], vf[4][2];                                                 \
    _Pragma("unroll") for (int kvt = 0; kvt < 2; ++kvt)                        \
      _Pragma("unroll") for (int s = 0; s < 4; ++s)                            \
        kf[kvt][s] = *(const bf16x8*)(lds + (B_) * 8192 + ka_[kvt * 4 + s]);   \
    _Pragma("unroll") for (int ks = 0; ks < 4; ++ks)                           \
      _Pragma("unroll") for (int et = 0; et < 2; ++et)                         \
        vf[ks][et] = *(const bf16x8*)(lds + (B_) * 8192 + va_[ks * 2 + et]);   \
    u32x4 pau[4];                                                              \
    _Pragma("unroll") for (int kvt = 0; kvt < 2; ++kvt) {                      \
      __builtin_amdgcn_s_setprio(1);                                           \
      f32x16 sa = MFMA32(kf[kvt][0], qf[0], FZ);                               \
      sa = MFMA32(kf[kvt][1], qf[1], sa);                                      \
      sa = MFMA32(kf[kvt][2], qf[2], sa);                                      \
      sa = MFMA32(kf[kvt][3], qf[3], sa);                                      \
      __builtin_amdgcn_s_setprio(0);                                           \
      unsigned c0, c1, c2, c3, c4, c5, c6, c7;                                 \
      PKPAIR(c0, 0) PKPAIR(c1, 1) PKPAIR(c2, 2) PKPAIR(c3, 3)                  \
      PKPAIR(c4, 4) PKPAIR(c5, 5) PKPAIR(c6, 6) PKPAIR(c7, 7)                  \
      asm("v_permlane32_swap_b32 %0, %1" : "+v"(c0), "+v"(c2));                \
      asm("v_permlane32_swap_b32 %0, %1" : "+v"(c1), "+v"(c3));                \
      asm("v_permlane32_swap_b32 %0, %1" : "+v"(c4), "+v"(c6));                \
      asm("v_permlane32_swap_b32 %0, %1" : "+v"(c5), "+v"(c7));                \
      pau[2 * kvt][0] = c0; pau[2 * kvt][1] = c1;                              \
      pau[2 * kvt][2] = c2; pau[2 * kvt][3] = c3;                              \
      pau[2 * kvt + 1][0] = c4; pau[2 * kvt + 1][1] = c5;                      \
      pau[2 * kvt + 1][2] = c6; pau[2 * kvt + 1][3] = c7;                      \
      lacc = MFMA32(__builtin_bit_cast(bf16x8, pau[2 * kvt]), onesf, lacc);    \
      lacc = MFMA32(__builtin_bit_cast(bf16x8, pau[2 * kvt + 1]), onesf, lacc);\
    }                                                                          \
    __builtin_amdgcn_s_setprio(1);                                             \
    _Pragma("unroll") for (int ks = 0; ks < 4; ++ks) {                         \
      bf16x8 paf = __builtin_bit_cast(bf16x8, pau[ks]);                        \
      cacc[0] = MFMA32(paf, vf[ks][0], cacc[0]);                               \
      cacc[1] = MFMA32(paf, vf[ks][1], cacc[1]);                               \
    }                                                                          \
    __builtin_amdgcn_s_setprio(0);                                             \
    __syncthreads();                                                           \
  }

  for (int t = 0; t < 32; t += 2) {
    TILEBODY(0, t)
    TILEBODY(1, t + 1)
  }
#undef TILEBODY
#undef PKPAIR
#undef STAGE

  // lacc[r] = full softmax denom for q-row ql(r,h) (same row map as cacc[*][r])
  const int b = bh / 12, hh = bh - b * 12;
#pragma unroll
  for (int r = 0; r < 16; ++r) {
    const int ql = (r & 3) + 8 * (r >> 2) + 4 * h;
    float rl = __builtin_amdgcn_rcpf(lacc[r]);
    size_t base = ((size_t)b * 2048 + q0 + ql) * 768 + hh * 64 + l31;
    ctx[base]      = (__bf16)(cacc[0][r] * rl);
    ctx[base + 32] = (__bf16)(cacc[1][r] * rl);
  }
}

// ---------------- LayerNorm over 768 (one row per block) ----------------
__global__ __launch_bounds__(256) void ln_kernel(
    const float* __restrict__ hb, const float* __restrict__ gamma,
    const float* __restrict__ beta, float* __restrict__ out) {
  __shared__ float ssum[4], ssq[4];
  const int row = blockIdx.x, t = threadIdx.x;
  const float* hr = hb + (size_t)row * 768;
  float v0 = hr[t], v1 = hr[t + 256], v2 = hr[t + 512];
  float sum = v0 + v1 + v2;
  float sq = v0 * v0 + v1 * v1 + v2 * v2;
#pragma unroll
  for (int mask = 1; mask < 64; mask <<= 1) {
    sum += __shfl_xor(sum, mask, 64);
    sq += __shfl_xor(sq, mask, 64);
  }
  const int w = t >> 6;
  if ((t & 63) == 0) { ssum[w] = sum; ssq[w] = sq; }
  __syncthreads();
  float s1 = ssum[0] + ssum[1] + ssum[2] + ssum[3];
  float s2 = ssq[0] + ssq[1] + ssq[2] + ssq[3];
  float mu = s1 * (1.0f / 768.0f);
  float var = s2 * (1.0f / 768.0f) - mu * mu;
  float rs = rsqrtf(var + 1e-5f);
  float* orow = out + (size_t)row * 768;
  orow[t]       = (v0 - mu) * rs * gamma[t]       + beta[t];
  orow[t + 256] = (v1 - mu) * rs * gamma[t + 256] + beta[t + 256];
  orow[t + 512] = (v2 - mu) * rs * gamma[t + 512] + beta[t + 512];
}

// ---------------- launch ----------------
extern "C" void kernel_launch(void* const* d_in, const int* in_sizes, int n_in,
                              void* d_out, int out_size, void* d_ws, size_t ws_size,
                              hipStream_t stream) {
  const float* x     = (const float*)d_in[0];
  const float* Wq    = (const float*)d_in[1];
  const float* bq    = (const float*)d_in[2];
  const float* Wk    = (const float*)d_in[3];
  const float* bk    = (const float*)d_in[4];
  const float* Wv    = (const float*)d_in[5];
  const float* bv    = (const float*)d_in[6];
  const float* Wo    = (const float*)d_in[7];
  const float* bo    = (const float*)d_in[8];
  const float* gamma = (const float*)d_in[9];
  const float* beta  = (const float*)d_in[10];
  float* out = (float*)d_out;

  char* ws = (char*)d_ws;
  __bf16* xb   = (__bf16*)(ws);                 // 12582912
  __bf16* wqkv = (__bf16*)(ws + 12582912);      //  3538944
  __bf16* wot  = (__bf16*)(ws + 16121856);      //  1179648
  __bf16* qb   = (__bf16*)(ws + 17301504);      // 12582912
  __bf16* kb   = (__bf16*)(ws + 29884416);      // 12582912
  __bf16* vt   = (__bf16*)(ws + 42467328);      // 12582912
  __bf16* ctx  = (__bf16*)(ws + 55050240);      // 12582912
  float*  hb   = (float*)(ws + 67633152);       // 25165824

  pack_kernel<<<dim3(1024), dim3(256), 0, stream>>>(x, Wq, Wk, Wv, Wo, xb, wqkv, wot);
  gemm_qkv<<<dim3(18, 64), dim3(256), 0, stream>>>(xb, wqkv, bq, bk, bv, qb, kb, vt);
  attn_kernel<<<dim3(48, 16), dim3(256), 0, stream>>>(qb, kb, vt, ctx);
  gemm_proj<<<dim3(6, 64), dim3(256), 0, stream>>>(ctx, wot, bo, x, hb);
  ln_kernel<<<dim3(8192), dim3(256), 0, stream>>>(hb, gamma, beta, out);
}

// Round 12
// 158.114 us; speedup vs baseline: 1.1323x; 1.1323x over previous
//
#include <hip/hip_runtime.h>

// B=4, S=2048, D=768, H=12, E=64, M=B*S=8192, N_qkv=2304
// scale = log2(e)/sqrt(S) folded into Q at QKV-GEMM epilogue (softmax via exp2).

typedef __bf16 bf16x8 __attribute__((ext_vector_type(8)));
typedef __bf16 bf16x4 __attribute__((ext_vector_type(4)));
typedef float  f32x4  __attribute__((ext_vector_type(4)));
typedef float  f32x16 __attribute__((ext_vector_type(16)));
typedef unsigned u32x4 __attribute__((ext_vector_type(4)));

#define MFMA16(a,b,c) __builtin_amdgcn_mfma_f32_16x16x32_bf16((a),(b),(c),0,0,0)
#define MFMA32(a,b,c) __builtin_amdgcn_mfma_f32_32x32x16_bf16((a),(b),(c),0,0,0)
// 1/sqrt(2048) * log2(e): scores land in log2 domain -> exp2 only, no mul.
#define QSCALE2 (0.022097086912079612f * 1.4426950408889634f)

__device__ __forceinline__ void gload16(const void* g, void* l) {
  __builtin_amdgcn_global_load_lds((const __attribute__((address_space(1))) void*)g,
                                   (__attribute__((address_space(3))) void*)l, 16, 0, 0);
}

// ---------------- pack: fp32 -> bf16 (+ weight transposes) ----------------
__global__ __launch_bounds__(256) void pack_kernel(
    const float* __restrict__ x, const float* __restrict__ Wq,
    const float* __restrict__ Wk, const float* __restrict__ Wv,
    const float* __restrict__ Wo,
    __bf16* __restrict__ xb, __bf16* __restrict__ wqkv, __bf16* __restrict__ wot) {
  int tid = blockIdx.x * 256 + threadIdx.x;
  int nth = gridDim.x * 256;
  for (int i = tid; i < 8192 * 768 / 4; i += nth) {
    float4 v = ((const float4*)x)[i];
    bf16x4 o; o[0] = (__bf16)v.x; o[1] = (__bf16)v.y; o[2] = (__bf16)v.z; o[3] = (__bf16)v.w;
    ((bf16x4*)xb)[i] = o;
  }
  for (int i = tid; i < 3 * 768 * 768; i += nth) {
    int n = i / 768, d = i - n * 768;
    int p = n / 768;
    int wn = n - p * 768;
    int h = wn >> 6, e = wn & 63;
    const float* W = (p == 0) ? Wq : (p == 1) ? Wk : Wv;
    wqkv[i] = (__bf16)W[(h * 768 + d) * 64 + e];
  }
  for (int i = tid; i < 768 * 768; i += nth) {
    int n = i / 768, k = i - n * 768;
    wot[i] = (__bf16)Wo[k * 768 + n];
  }
}

// ---- GEMM core v12: 128x128 tile, BK=64, single buffer, 12 K-steps ----------
// r8-r11 established: per-K-step fixed overhead (2 barriers + ds_read latency +
// issue serialization ~1540cy vs ~300cy work) dominates, and scheduling changes
// (dbuf r9, counted-vmcnt r11) don't reduce it. BK=64 halves the step count:
// 12 steps x (8 gloads; barrier; 2x(8 ds_read_b128 + 16 MFMA); barrier).
// LDS 2x16KB = 32KB single-buffered (m132's BK=128/64KB occupancy cliff avoided).
// 128B rows need the attn-proven XOR swizzle: LDS dest linear, global SOURCE
// pre-swizzled byte^=((row&7)<<4), read col XOR'd the same. Read pattern
// (16 rows x 4 hi) ^ (ln&7) -> uniform 8 lanes per 16B slot = conflict-free.
#define GEMM_CORE(A_, Bt_, m0_, n0_)                                              \
  __shared__ __align__(16) __bf16 As[128 * 64];                                   \
  __shared__ __align__(16) __bf16 Bs[128 * 64];                                   \
  const int tid = threadIdx.x;                                                    \
  const int w = tid >> 6, lane = tid & 63, ln = lane & 15, hi = lane >> 4;        \
  const int wr = w >> 1, wc = w & 1;                                              \
  f32x4 acc[4][4];                                                                \
  {                                                                               \
    f32x4 z = {0.f, 0.f, 0.f, 0.f};                                               \
    _Pragma("unroll") for (int i = 0; i < 4; ++i)                                 \
      _Pragma("unroll") for (int j = 0; j < 4; ++j) acc[i][j] = z;                \
  }                                                                               \
  const int colx0 = ((hi) ^ (ln & 7)) << 4;      /* kk=0 read col (swizzled) */   \
  const int colx1 = ((4 + hi) ^ (ln & 7)) << 4;  /* kk=1 read col (swizzled) */   \
  {                                                                               \
    const int r0 = tid >> 3;                       /* staged row (per 32-group) */\
    const int scb = ((tid & 7) * 16) ^ ((r0 & 7) << 4);  /* pre-swizzled src */   \
    const char* gA = (const char*)(A_) + (size_t)(m0_ + r0) * 1536 + scb;         \
    const char* gB = (const char*)(Bt_) + (size_t)(n0_ + r0) * 1536 + scb;        \
    char* lA = (char*)As + w * 1024;   /* wave-uniform dest (lane*16 implicit) */ \
    char* lB = (char*)Bs + w * 1024;                                              \
    for (int kt = 0; kt < 12; ++kt) {                                             \
      const int kb = kt * 128;                                                    \
      _Pragma("unroll") for (int j = 0; j < 4; ++j) {                             \
        gload16(gA + j * 49152 + kb, lA + j * 4096);                              \
        gload16(gB + j * 49152 + kb, lB + j * 4096);                              \
      }                                                                           \
      __syncthreads();                                                            \
      _Pragma("unroll") for (int kk = 0; kk < 2; ++kk) {                          \
        const int cx = kk ? colx1 : colx0;                                        \
        bf16x8 af[4], bfv[4];                                                     \
        _Pragma("unroll") for (int mt = 0; mt < 4; ++mt)                          \
          af[mt] = *(const bf16x8*)((char*)As + (wr * 64 + mt * 16 + ln) * 128 + cx); \
        _Pragma("unroll") for (int nt = 0; nt < 4; ++nt)                          \
          bfv[nt] = *(const bf16x8*)((char*)Bs + (wc * 64 + nt * 16 + ln) * 128 + cx); \
        _Pragma("unroll") for (int mt = 0; mt < 4; ++mt)                          \
          _Pragma("unroll") for (int nt = 0; nt < 4; ++nt)                        \
            acc[mt][nt] = MFMA16(af[mt], bfv[nt], acc[mt][nt]);                   \
      }                                                                           \
      __syncthreads();                                                            \
    }                                                                             \
  }

__global__ __launch_bounds__(256) void gemm_qkv(
    const __bf16* __restrict__ A, const __bf16* __restrict__ Bt,
    const float* __restrict__ bq, const float* __restrict__ bk,
    const float* __restrict__ bv,
    __bf16* __restrict__ qb, __bf16* __restrict__ kb, __bf16* __restrict__ vt) {
  // T1: XCD-aware bijective swizzle (nwg=1152, 144/XCD; consecutive swz share A-panels)
  const int lin = blockIdx.y * 18 + blockIdx.x;
  const int swzb = (lin & 7) * 144 + (lin >> 3);
  const int m0 = (swzb / 18) * 128, n0 = (swzb % 18) * 128;
  GEMM_CORE(A, Bt, m0, n0)
  const int p = n0 / 768;
  const float* bias = (p == 0) ? bq : (p == 1) ? bk : bv;
  const float sc = (p == 0) ? QSCALE2 : 1.0f;
#pragma unroll
  for (int nt = 0; nt < 4; ++nt) {
    int n = n0 + wc * 64 + nt * 16 + ln;
    int wn = n - p * 768;
    int h = wn >> 6, e = wn & 63;
    float bb = bias[wn];
#pragma unroll
    for (int mt = 0; mt < 4; ++mt) {
      int mrow = m0 + wr * 64 + mt * 16 + hi * 4;
      int b = mrow >> 11, s0 = mrow & 2047;
      if (p == 2) {
        bf16x4 pk;
#pragma unroll
        for (int r = 0; r < 4; ++r) pk[r] = (__bf16)(acc[mt][nt][r] + bb);
        *(bf16x4*)&vt[(((size_t)b * 12 + h) * 64 + e) * 2048 + s0] = pk;
      } else {
        __bf16* dst = (p == 0) ? qb : kb;
#pragma unroll
        for (int r = 0; r < 4; ++r)
          dst[(((size_t)b * 12 + h) * 2048 + s0 + r) * 64 + e] =
              (__bf16)((acc[mt][nt][r] + bb) * sc);
      }
    }
  }
}

// v12: h stored as bf16 (halves write), residual read from xb (bf16, halves
// read). LN tolerates bf16 h: adds ~0.01-0.02 absmax vs 0.099 threshold.
__global__ __launch_bounds__(256) void gemm_proj(
    const __bf16* __restrict__ A, const __bf16* __restrict__ Bt,
    const float* __restrict__ bo, const __bf16* __restrict__ xres,
    __bf16* __restrict__ hout) {
  // T1 swizzle (nwg=384, 48/XCD)
  const int lin = blockIdx.y * 6 + blockIdx.x;
  const int swzb = (lin & 7) * 48 + (lin >> 3);
  const int m0 = (swzb / 6) * 128, n0 = (swzb % 6) * 128;
  GEMM_CORE(A, Bt, m0, n0)
#pragma unroll
  for (int nt = 0; nt < 4; ++nt) {
    int n = n0 + wc * 64 + nt * 16 + ln;
    float bb = bo[n];
#pragma unroll
    for (int mt = 0; mt < 4; ++mt) {
      int mrow = m0 + wr * 64 + mt * 16 + hi * 4;
#pragma unroll
      for (int r = 0; r < 4; ++r) {
        size_t idx = (size_t)(mrow + r) * 768 + n;
        hout[idx] = (__bf16)(acc[mt][nt][r] + bb + (float)xres[idx]);
      }
    }
  }
}

// ---------------- flash attention: 32x32 MFMA, in-register P, swizzled LDS ----
// ROUND-4 VERSION (best measured: 69us). grid (48,16): block = (b*12+h, 128 q).
// 4 waves x 32 q-rows. KVBLK=64. Swapped mfma(K,Q): lane (q=lane&31, h=lane>>5)
// holds P[q][kv=(r&3)+8*(r>>2)+4h]. cvt_pk + permlane32_swap builds PV A-frags
// in-register. K/V tiles [64][64] bf16, XOR-swizzle byte^=((row&7)<<4), staged
// via global_load_lds with pre-swizzled global SOURCE; ^32s col steps (XOR dom).
// lsum via MFMA(P, ones): lacc[r] = denom for the SAME q-row as cacc[*][r].
// Structure at its floor at 3 waves/SIMD (reg-capped); v5 no-LDS, v6 T15,
// v7 kv-split all refuted alternatives. blockIdx identity: XCD = bh%8.
__global__ __launch_bounds__(256, 3) void attn_kernel(
    const __bf16* __restrict__ qb, const __bf16* __restrict__ kb,
    const __bf16* __restrict__ vt, __bf16* __restrict__ ctx) {
  // LDS: K dbuf [2][8KB] at 0, V^T dbuf [2][8KB] at 16384. 32 KiB total.
  __shared__ __align__(16) char lds[32768];
  const int tid = threadIdx.x;
  const int w = tid >> 6, lane = tid & 63;
  const int l31 = lane & 31, h = lane >> 5;
  const int bh = blockIdx.x;
  const int q0 = blockIdx.y * 128 + w * 32;

  // ---- staging: thread covers linear LDS bytes o=tid*16 (round0) and +4096 (round1)
  const int o0 = tid * 16, o1 = o0 + 4096;
  const int r0s = o0 >> 7, cb0 = o0 & 127;
  const int r1s = o1 >> 7, cb1 = o1 & 127;
  const char* kgb = (const char*)(kb + (size_t)bh * 2048 * 64);
  const char* vgb = (const char*)(vt + (size_t)bh * 64 * 2048);
  const char* ksrc0 = kgb + r0s * 128 + (cb0 ^ ((r0s & 7) << 4));
  const char* ksrc1 = kgb + r1s * 128 + (cb1 ^ ((r1s & 7) << 4));
  const char* vsrc0 = vgb + r0s * 4096 + (cb0 ^ ((r0s & 7) << 4));
  const char* vsrc1 = vgb + r1s * 4096 + (cb1 ^ ((r1s & 7) << 4));
  char* kl0 = lds + w * 1024;            // wave-uniform LDS base (lane*16 implicit)
  char* vl0 = lds + 16384 + w * 1024;

#define STAGE(t_, b_) do {                                   \
    gload16(ksrc0 + (size_t)(t_) * 8192, kl0 + (b_) * 8192); \
    gload16(ksrc1 + (size_t)(t_) * 8192, kl0 + (b_) * 8192 + 4096); \
    gload16(vsrc0 + (size_t)(t_) * 128,  vl0 + (b_) * 8192); \
    gload16(vsrc1 + (size_t)(t_) * 128,  vl0 + (b_) * 8192 + 4096); \
  } while (0)

  // ---- Q fragments (B-operand of mfma(K,Q)): col=q=l31, k(e)=16s+8h+j
  const __bf16* qp = qb + ((size_t)bh * 2048 + q0 + l31) * 64 + h * 8;
  bf16x8 qf[4];
#pragma unroll
  for (int s = 0; s < 4; ++s) qf[s] = *(const bf16x8*)(qp + 16 * s);

  // ---- per-lane swizzled LDS read addresses, precomputed (loop-invariant)
  const int swz = (l31 & 7) << 4;
  const int krd = l31 * 128 + ((h * 16) ^ swz);
  const int vrd = 16384 + l31 * 128 + ((h * 16) ^ swz);
  int ka_[8], va_[8];
#pragma unroll
  for (int kvt = 0; kvt < 2; ++kvt)
#pragma unroll
    for (int s = 0; s < 4; ++s) ka_[kvt * 4 + s] = (krd + kvt * 4096) ^ (s * 32);
#pragma unroll
  for (int ks = 0; ks < 4; ++ks)
#pragma unroll
    for (int et = 0; et < 2; ++et) va_[ks * 2 + et] = (vrd + et * 4096) ^ (ks * 32);

  // ---- loop-invariant constants: zero C-init, ones B-frag for lsum-MFMA
  f32x16 FZ;
#pragma unroll
  for (int r = 0; r < 16; ++r) FZ[r] = 0.f;
  bf16x8 onesf;
#pragma unroll
  for (int j = 0; j < 8; ++j) onesf[j] = (__bf16)1.0f;

  f32x16 lacc = FZ;
  f32x16 cacc[2];
  cacc[0] = FZ; cacc[1] = FZ;

  STAGE(0, 0);
  __syncthreads();

#define PKPAIR(dst_, i_)                                                       \
  {                                                                            \
    float pa_ = __builtin_amdgcn_exp2f(sa[2 * (i_)]);                          \
    float pb_ = __builtin_amdgcn_exp2f(sa[2 * (i_) + 1]);                      \
    asm("v_cvt_pk_bf16_f32 %0, %1, %2" : "=v"(dst_) : "v"(pa_), "v"(pb_));     \
  }

#define TILEBODY(B_, T_)                                                       \
  {                                                                            \
    if ((T_) < 31) STAGE((T_) + 1, (B_) ^ 1);                                  \
    bf16x8 kf[2][4], vf[4][2];                                                 \
    _Pragma("unroll") for (int kvt = 0; kvt < 2; ++kvt)                        \
      _Pragma("unroll") for (int s = 0; s < 4; ++s)                            \
        kf[kvt][s] = *(const bf16x8*)(lds + (B_) * 8192 + ka_[kvt * 4 + s]);   \
    _Pragma("unroll") for (int ks = 0; ks < 4; ++ks)                           \
      _Pragma("unroll") for (int et = 0; et < 2; ++et)                         \
        vf[ks][et] = *(const bf16x8*)(lds + (B_) * 8192 + va_[ks * 2 + et]);   \
    u32x4 pau[4];                                                              \
    _Pragma("unroll") for (int kvt = 0; kvt < 2; ++kvt) {                      \
      __builtin_amdgcn_s_setprio(1);                                           \
      f32x16 sa = MFMA32(kf[kvt][0], qf[0], FZ);                               \
      sa = MFMA32(kf[kvt][1], qf[1], sa);                                      \
      sa = MFMA32(kf[kvt][2], qf[2], sa);                                      \
      sa = MFMA32(kf[kvt][3], qf[3], sa);                                      \
      __builtin_amdgcn_s_setprio(0);                                           \
      unsigned c0, c1, c2, c3, c4, c5, c6, c7;                                 \
      PKPAIR(c0, 0) PKPAIR(c1, 1) PKPAIR(c2, 2) PKPAIR(c3, 3)                  \
      PKPAIR(c4, 4) PKPAIR(c5, 5) PKPAIR(c6, 6) PKPAIR(c7, 7)                  \
      asm("v_permlane32_swap_b32 %0, %1" : "+v"(c0), "+v"(c2));                \
      asm("v_permlane32_swap_b32 %0, %1" : "+v"(c1), "+v"(c3));                \
      asm("v_permlane32_swap_b32 %0, %1" : "+v"(c4), "+v"(c6));                \
      asm("v_permlane32_swap_b32 %0, %1" : "+v"(c5), "+v"(c7));                \
      pau[2 * kvt][0] = c0; pau[2 * kvt][1] = c1;                              \
      pau[2 * kvt][2] = c2; pau[2 * kvt][3] = c3;                              \
      pau[2 * kvt + 1][0] = c4; pau[2 * kvt + 1][1] = c5;                      \
      pau[2 * kvt + 1][2] = c6; pau[2 * kvt + 1][3] = c7;                      \
      lacc = MFMA32(__builtin_bit_cast(bf16x8, pau[2 * kvt]), onesf, lacc);    \
      lacc = MFMA32(__builtin_bit_cast(bf16x8, pau[2 * kvt + 1]), onesf, lacc);\
    }                                                                          \
    __builtin_amdgcn_s_setprio(1);                                             \
    _Pragma("unroll") for (int ks = 0; ks < 4; ++ks) {                         \
      bf16x8 paf = __builtin_bit_cast(bf16x8, pau[ks]);                        \
      cacc[0] = MFMA32(paf, vf[ks][0], cacc[0]);                               \
      cacc[1] = MFMA32(paf, vf[ks][1], cacc[1]);                               \
    }                                                                          \
    __builtin_amdgcn_s_setprio(0);                                             \
    __syncthreads();                                                           \
  }

  for (int t = 0; t < 32; t += 2) {
    TILEBODY(0, t)
    TILEBODY(1, t + 1)
  }
#undef TILEBODY
#undef PKPAIR
#undef STAGE

  // lacc[r] = full softmax denom for q-row ql(r,h) (same row map as cacc[*][r])
  const int b = bh / 12, hh = bh - b * 12;
#pragma unroll
  for (int r = 0; r < 16; ++r) {
    const int ql = (r & 3) + 8 * (r >> 2) + 4 * h;
    float rl = __builtin_amdgcn_rcpf(lacc[r]);
    size_t base = ((size_t)b * 2048 + q0 + ql) * 768 + hh * 64 + l31;
    ctx[base]      = (__bf16)(cacc[0][r] * rl);
    ctx[base + 32] = (__bf16)(cacc[1][r] * rl);
  }
}

// ---------------- LayerNorm over 768 (one row per block, bf16 h) ----------------
__global__ __launch_bounds__(256) void ln_kernel(
    const __bf16* __restrict__ hb, const float* __restrict__ gamma,
    const float* __restrict__ beta, float* __restrict__ out) {
  __shared__ float ssum[4], ssq[4];
  const int row = blockIdx.x, t = threadIdx.x;
  const __bf16* hr = hb + (size_t)row * 768;
  float v0 = (float)hr[t], v1 = (float)hr[t + 256], v2 = (float)hr[t + 512];
  float sum = v0 + v1 + v2;
  float sq = v0 * v0 + v1 * v1 + v2 * v2;
#pragma unroll
  for (int mask = 1; mask < 64; mask <<= 1) {
    sum += __shfl_xor(sum, mask, 64);
    sq += __shfl_xor(sq, mask, 64);
  }
  const int w = t >> 6;
  if ((t & 63) == 0) { ssum[w] = sum; ssq[w] = sq; }
  __syncthreads();
  float s1 = ssum[0] + ssum[1] + ssum[2] + ssum[3];
  float s2 = ssq[0] + ssq[1] + ssq[2] + ssq[3];
  float mu = s1 * (1.0f / 768.0f);
  float var = s2 * (1.0f / 768.0f) - mu * mu;
  float rs = rsqrtf(var + 1e-5f);
  float* orow = out + (size_t)row * 768;
  orow[t]       = (v0 - mu) * rs * gamma[t]       + beta[t];
  orow[t + 256] = (v1 - mu) * rs * gamma[t + 256] + beta[t + 256];
  orow[t + 512] = (v2 - mu) * rs * gamma[t + 512] + beta[t + 512];
}

// ---------------- launch ----------------
extern "C" void kernel_launch(void* const* d_in, const int* in_sizes, int n_in,
                              void* d_out, int out_size, void* d_ws, size_t ws_size,
                              hipStream_t stream) {
  const float* x     = (const float*)d_in[0];
  const float* Wq    = (const float*)d_in[1];
  const float* bq    = (const float*)d_in[2];
  const float* Wk    = (const float*)d_in[3];
  const float* bk    = (const float*)d_in[4];
  const float* Wv    = (const float*)d_in[5];
  const float* bv    = (const float*)d_in[6];
  const float* Wo    = (const float*)d_in[7];
  const float* bo    = (const float*)d_in[8];
  const float* gamma = (const float*)d_in[9];
  const float* beta  = (const float*)d_in[10];
  float* out = (float*)d_out;

  char* ws = (char*)d_ws;
  __bf16* xb   = (__bf16*)(ws);                 // 12582912
  __bf16* wqkv = (__bf16*)(ws + 12582912);      //  3538944
  __bf16* wot  = (__bf16*)(ws + 16121856);      //  1179648
  __bf16* qb   = (__bf16*)(ws + 17301504);      // 12582912
  __bf16* kb   = (__bf16*)(ws + 29884416);      // 12582912
  __bf16* vt   = (__bf16*)(ws + 42467328);      // 12582912
  __bf16* ctx  = (__bf16*)(ws + 55050240);      // 12582912
  __bf16* hb   = (__bf16*)(ws + 67633152);      // 12582912 (bf16 now)

  pack_kernel<<<dim3(1024), dim3(256), 0, stream>>>(x, Wq, Wk, Wv, Wo, xb, wqkv, wot);
  gemm_qkv<<<dim3(18, 64), dim3(256), 0, stream>>>(xb, wqkv, bq, bk, bv, qb, kb, vt);
  attn_kernel<<<dim3(48, 16), dim3(256), 0, stream>>>(qb, kb, vt, ctx);
  gemm_proj<<<dim3(6, 64), dim3(256), 0, stream>>>(ctx, wot, bo, xb, hb);
  ln_kernel<<<dim3(8192), dim3(256), 0, stream>>>(hb, gamma, beta, out);
}